// Round 2
// baseline (134.869 us; speedup 1.0000x reference)
//
#include <hip/hip_runtime.h>
#include <hip/hip_bf16.h>

// Problem: features_1 [1,20000,256] f32, features_2 [1,8192,256] f32, map21 [8192] int
#define PP      8192
#define DIM     256
#define DIMP    272              // 256 + 16 pad dims (norm embedding in 4 of them)
#define NKF     17               // K fragments of 16
#define GS      (32 * DIMP)      // 8704 bf16 elems per 32-row group
#define NCHUNK  16               // column chunks (grid.y); chunk = 512 cols
#define TCOLS   16               // 32-col tiles per chunk
#define ROWBLK  256              // rows per main block (4 waves x 64)
#define NROWBLK (PP / ROWBLK)    // 32
#define TILEB   (32 * DIMP * 2)  // 17408 B per 32-col B tile
#define NBUF    4                // LDS ring buffers (depth-3 prefetch)

typedef __bf16 bf16_t;
using bf16x8 = __attribute__((ext_vector_type(8))) __bf16;
using bf16x4 = __attribute__((ext_vector_type(4))) __bf16;
using f32x4  = __attribute__((ext_vector_type(4))) float;
using f32x16 = __attribute__((ext_vector_type(16))) float;

typedef __attribute__((address_space(1))) void as1_void;
typedef __attribute__((address_space(3))) void as3_void;

#define C2    20.609929155556618          // 1/(T*ln2): -dist -> log2-domain logit
#define MEXP  (-340.0f)                   // fixed log2 shift (safe: see analysis)
#define COEF  ((float)(-(C2 * 1.4142135623730951) * 8388608.0))  // -C2*sqrt(2)*2^23
#define KBIAS ((float)((127.0 + 340.0) * 8388608.0))             // (127 - MEXP)*2^23
#define LN2   0.6931471805599453f

// ---------------------------------------------------------------------------
// Kernel 1: gather + bf16 convert into frag-major layout + norm-embedding pad
// dims + exact fp32 diagonal logit. Also zero-inits part_l / counters / out.
// One wave per row p; lane covers k = lane*4 .. +3.   (UNCHANGED)
// ---------------------------------------------------------------------------
__global__ __launch_bounds__(256) void nce_prep(
    const float* __restrict__ f1, const float* __restrict__ f2,
    const int* __restrict__ map,
    bf16_t* __restrict__ qb2, bf16_t* __restrict__ kb2,
    float* __restrict__ diag2, float* __restrict__ part_l,
    unsigned* __restrict__ cnt, float* __restrict__ out)
{
    const int tid  = threadIdx.x;
    const int wave = tid >> 6, lane = tid & 63;
    const int p    = blockIdx.x * 4 + wave;
    const int gtid = blockIdx.x * 256 + tid;

    if (gtid < PP) part_l[gtid] = 0.0f;
    if (gtid < NROWBLK) cnt[gtid] = 0u;
    if (gtid == 0) out[0] = 0.0f;

    const int idx = map[p];
    const f32x4 qv = *(const f32x4*)(f1 + (size_t)idx * DIM + lane * 4);
    const f32x4 kv = *(const f32x4*)(f2 + (size_t)p * DIM + lane * 4);

    float qs = qv[0]*qv[0] + qv[1]*qv[1] + qv[2]*qv[2] + qv[3]*qv[3];
    float ks = kv[0]*kv[0] + kv[1]*kv[1] + kv[2]*kv[2] + kv[3]*kv[3];
    const f32x4 dv = qv - kv;
    float ds = dv[0]*dv[0] + dv[1]*dv[1] + dv[2]*dv[2] + dv[3]*dv[3];

    bf16x4 qo, ko;
    #pragma unroll
    for (int i = 0; i < 4; ++i) { qo[i] = (bf16_t)qv[i]; ko[i] = (bf16_t)kv[i]; }

    const int G = p >> 5, l31 = p & 31;
    const int kk = lane >> 2, h = (lane >> 1) & 1, j0 = (lane & 1) * 4;
    const size_t base = (size_t)G * GS;
    const size_t off  = base + (size_t)(kk * 64 + h * 32 + l31) * 8 + j0;
    *(bf16x4*)(qb2 + off) = qo;
    *(bf16x4*)(kb2 + off) = ko;

    #pragma unroll
    for (int s = 32; s > 0; s >>= 1) {
        qs += __shfl_xor(qs, s);
        ks += __shfl_xor(ks, s);
        ds += __shfl_xor(ds, s);
    }

    // Pad frag kk=16 (dims 256..271). q' = [qhi,qlo,1,1,0..], k' = [1,1,khi,klo,0..]
    // so extra-dim dot = -(qs+ks)/2 with bf16 hi/lo split (norm error < 0.01).
    if (lane < 4) {
        const int hh = lane & 1;           // h of the pad block this lane writes
        bf16x8 v;
        #pragma unroll
        for (int i = 0; i < 8; ++i) v[i] = (bf16_t)0.0f;
        if (lane == 0) {                   // q', dims 256..263
            const float qh = -0.5f * qs;
            const bf16_t q1 = (bf16_t)qh;
            v[0] = q1; v[1] = (bf16_t)(qh - (float)q1);
            v[2] = (bf16_t)1.0f; v[3] = (bf16_t)1.0f;
        } else if (lane == 2) {            // k', dims 256..263
            const float kh = -0.5f * ks;
            const bf16_t k1 = (bf16_t)kh;
            v[0] = (bf16_t)1.0f; v[1] = (bf16_t)1.0f;
            v[2] = k1; v[3] = (bf16_t)(kh - (float)k1);
        }
        bf16_t* dstp = (lane < 2) ? qb2 : kb2;
        *(bf16x8*)(dstp + base + (size_t)(1024 + hh * 32 + l31) * 8) = v;
    }
    if (lane == 0)
        diag2[p] = (float)(-C2) * __builtin_amdgcn_sqrtf(ds);  // exact diag, log2
}

// ---------------------------------------------------------------------------
// Stage one 32-col B tile (17408 B, frag-major) into LDS via global_load_lds
// width-16. LDS dst = wave-uniform base (+ implicit lane*16).
// Waves 0-3 load 4x1KB each; wave 0 loads the 17th-fragment KB extra (5 loads).
// ---------------------------------------------------------------------------
__device__ __forceinline__ void stage(const bf16_t* __restrict__ kb2,
                                      int Gc, int wave, int lane, char* dst)
{
    __builtin_assume(wave >= 0 && wave < 4);
    __builtin_assume(lane >= 0 && lane < 64);
    const bf16_t* src = kb2 + (size_t)Gc * GS + wave * 512 + lane * 8;
    char* d = dst + wave * 1024;
    #pragma unroll
    for (int j = 0; j < 4; ++j)
        __builtin_amdgcn_global_load_lds((const as1_void*)(src + j * 2048),
                                         (as3_void*)(d + j * 4096), 16, 0, 0);
    if (wave == 0)   // last 1 KB (17th fragment block)
        __builtin_amdgcn_global_load_lds((const as1_void*)(src + 4 * 2048),
                                         (as3_void*)(d + 4 * 4096), 16, 0, 0);
}

// ---------------------------------------------------------------------------
// One pipeline phase: counted-vmcnt wait (+ lgkmcnt(0) race guard) + raw
// barrier (prefetch loads stay in flight across it), issue prefetch for tile
// t+3, then ds_read + MFMA tile t under setprio(1), then sqrt/exp2 epilogue.
// N_WAIT = 4 * (#stages that must stay in flight) = 8 steady-state.
// (wave0 has 5 loads/stage, so vmcnt(8) over-waits it by <=2 loads — benign,
//  vmcnt retires in order.  lgkmcnt(0) is already-drained in steady state —
//  compiler waits ds_read->MFMA — so it's free; it provably closes the
//  "barrier crossed with ds_read of the to-be-overwritten buffer still in
//  flight" race.)
// ---------------------------------------------------------------------------
template<int N_WAIT, bool DO_PRE>
__device__ __forceinline__ void tile_phase(
    const bf16_t* __restrict__ kb2, int pre_cg,
    char* bufcur, char* bufpre, int wave, int lane,
    const bf16x8* __restrict__ a0, const bf16x8* __restrict__ a1,
    float* __restrict__ l0, float* __restrict__ l1)
{
    // counted wait: oldest stage retired, newer stages remain in flight
    asm volatile("s_waitcnt vmcnt(%c0) lgkmcnt(0)\n\ts_barrier"
                 :: "i"(N_WAIT) : "memory");
    if (DO_PRE) {
        stage(kb2, pre_cg, wave, lane, bufpre);
        // keep VMEM/DS order (stage issued before ds_reads); ALU may cross
        __builtin_amdgcn_sched_barrier(0x7);
    }
    const bf16_t* bp = (const bf16_t*)bufcur + lane * 8;
    f32x16 acc0 = {0,0,0,0,0,0,0,0,0,0,0,0,0,0,0,0};
    f32x16 acc1 = {0,0,0,0,0,0,0,0,0,0,0,0,0,0,0,0};
    __builtin_amdgcn_s_setprio(1);
    #pragma unroll
    for (int kk = 0; kk < NKF; ++kk) {
        const bf16x8 b = *(const bf16x8*)(bp + kk * 512);
        acc0 = __builtin_amdgcn_mfma_f32_32x32x16_bf16(a0[kk], b, acc0, 0, 0, 0);
        acc1 = __builtin_amdgcn_mfma_f32_32x32x16_bf16(a1[kk], b, acc1, 0, 0, 0);
    }
    __builtin_amdgcn_s_setprio(0);
    // acc = -dist^2/2.  2^(lg - MEXP) via bitcast trick:
    //   u = (u32)(t*COEF + KBIAS), t = sqrt(dist^2/2); negative -> clamp 0.
    #pragma unroll
    for (int i = 0; i < 16; ++i) {
        const float t0 = __builtin_amdgcn_sqrtf(-acc0[i]);
        const float u0 = fmaxf(fmaf(t0, COEF, KBIAS), 0.0f);
        l0[i] += __uint_as_float((unsigned)u0);
        const float t1 = __builtin_amdgcn_sqrtf(-acc1[i]);
        const float u1 = fmaxf(fmaf(t1, COEF, KBIAS), 0.0f);
        l1[i] += __uint_as_float((unsigned)u1);
    }
}

// ---------------------------------------------------------------------------
// Kernel 2: fused (QK' GEMM -> -dist^2/2) + fixed-shift exp2 accumulation +
// cross-block merge via atomicAdd + last-block final loss reduction.
// Wave = 64 rows (2 groups) x 32 cols; block = 4 waves = 256 rows.
// 4-buffer LDS ring, depth-3 prefetch, counted vmcnt (never 0 mid-loop),
// raw s_barrier (one per tile), setprio around MFMA cluster.
// ---------------------------------------------------------------------------
__global__ __launch_bounds__(256, 2) void nce_main(
    const bf16_t* __restrict__ qb2, const bf16_t* __restrict__ kb2,
    const float* __restrict__ diag2, float* __restrict__ part_l,
    unsigned* __restrict__ cnt, float* __restrict__ out)
{
    const int tid  = threadIdx.x, wave = tid >> 6, lane = tid & 63;
    const int l31  = lane & 31, h = lane >> 5;
    const int rb   = blockIdx.x;               // row-block 0..31 (256 rows)
    const int G0   = rb * 8 + wave * 2;        // this wave's first 32-row group
    const int c0g  = blockIdx.y * TCOLS;       // first col-group of chunk

    __shared__ __align__(16) char smem[NBUF][TILEB];
    __shared__ int s_last;

    // prologue: fill 3 of 4 ring slots (loads in flight behind the A-loads)
    stage(kb2, c0g + 0, wave, lane, smem[0]);
    stage(kb2, c0g + 1, wave, lane, smem[1]);
    stage(kb2, c0g + 2, wave, lane, smem[2]);

    // A fragments for 2 row groups: 2 x 17 x 4 = 136 VGPRs, 1KB/instr coalesced
    bf16x8 a0[NKF], a1[NKF];
    {
        const bf16_t* ap0 = qb2 + (size_t)G0 * GS + lane * 8;
        const bf16_t* ap1 = ap0 + GS;
        #pragma unroll
        for (int kk = 0; kk < NKF; ++kk) {
            a0[kk] = *(const bf16x8*)(ap0 + kk * 512);
            a1[kk] = *(const bf16x8*)(ap1 + kk * 512);
        }
    }

    float l0[16], l1[16];
    #pragma unroll
    for (int i = 0; i < 16; ++i) { l0[i] = 0.0f; l1[i] = 0.0f; }

    // steady state: tiles t0..t0+3 in bufs 0..3; prefetch t+3 each phase.
    for (int tb = 0; tb < 3; ++tb) {
        const int t0 = c0g + tb * 4;
        tile_phase<8, true >(kb2, t0 + 3, smem[0], smem[3], wave, lane, a0, a1, l0, l1);
        tile_phase<8, true >(kb2, t0 + 4, smem[1], smem[0], wave, lane, a0, a1, l0, l1);
        tile_phase<8, true >(kb2, t0 + 5, smem[2], smem[1], wave, lane, a0, a1, l0, l1);
        tile_phase<8, true >(kb2, t0 + 6, smem[3], smem[2], wave, lane, a0, a1, l0, l1);
    }
    // tail: t = 12..15 (stage 15 issued at t=12; drain 8 -> 8 -> 4 -> 0)
    tile_phase<8, true >(kb2, c0g + 15, smem[0], smem[3], wave, lane, a0, a1, l0, l1);
    tile_phase<8, false>(kb2, 0,        smem[1], nullptr, wave, lane, a0, a1, l0, l1);
    tile_phase<4, false>(kb2, 0,        smem[2], nullptr, wave, lane, a0, a1, l0, l1);
    tile_phase<0, false>(kb2, 0,        smem[3], nullptr, wave, lane, a0, a1, l0, l1);

    // sum l across the 32 column-lanes (plain adds — fixed shift, no max merge)
    #pragma unroll
    for (int s = 1; s < 32; s <<= 1) {
        #pragma unroll
        for (int i = 0; i < 16; ++i) {
            l0[i] += __shfl_xor(l0[i], s);
            l1[i] += __shfl_xor(l1[i], s);
        }
    }

    if (l31 == 0) {
        #pragma unroll
        for (int i = 0; i < 16; ++i) {
            const int r = (i & 3) + 8 * (i >> 2) + 4 * h;
            atomicAdd(&part_l[G0 * 32 + r], l0[i]);
            atomicAdd(&part_l[(G0 + 1) * 32 + r], l1[i]);
        }
    }

    __syncthreads();
    if (tid == 0) {
        __threadfence();
        s_last = (atomicAdd(&cnt[rb], 1u) == NCHUNK - 1) ? 1 : 0;
    }
    __syncthreads();
    if (s_last) {
        // all 16 chunk-blocks of this row-block done: finalize 256 rows
        const int row = rb * ROWBLK + tid;
        const float lf = atomicAdd(&part_l[row], 0.0f);   // coherent read
        float v = MEXP + __builtin_amdgcn_logf(lf) - diag2[row];  // log2 domain
        #pragma unroll
        for (int s = 1; s < 64; s <<= 1) v += __shfl_xor(v, s);
        __shared__ float red[4];
        if (lane == 0) red[wave] = v;
        __syncthreads();
        if (tid == 0)
            atomicAdd(out, (red[0] + red[1] + red[2] + red[3]) * (LN2 / (float)PP));
    }
}

// ---------------------------------------------------------------------------
extern "C" void kernel_launch(void* const* d_in, const int* in_sizes, int n_in,
                              void* d_out, int out_size, void* d_ws, size_t ws_size,
                              hipStream_t stream)
{
    const float* f1  = (const float*)d_in[0];   // [20000,256] f32
    const float* f2  = (const float*)d_in[1];   // [8192,256] f32
    const int*   map = (const int*)d_in[2];     // [8192] int
    float* out = (float*)d_out;

    // workspace layout (~8.98 MB)
    char* ws = (char*)d_ws;
    bf16_t*   qb2    = (bf16_t*)ws;                           // 256*8704*2 B
    bf16_t*   kb2    = qb2 + (size_t)256 * GS;                // 256*8704*2 B
    float*    diag2  = (float*)(ws + 2ull * 256 * GS * sizeof(bf16_t));
    float*    part_l = diag2 + PP;
    unsigned* cnt    = (unsigned*)(part_l + PP);

    nce_prep<<<PP / 4, 256, 0, stream>>>(f1, f2, map, qb2, kb2, diag2,
                                         part_l, cnt, out);
    nce_main<<<dim3(NROWBLK, NCHUNK), 256, 0, stream>>>(qb2, kb2, diag2,
                                                        part_l, cnt, out);
}

// Round 3
// 118.197 us; speedup vs baseline: 1.1411x; 1.1411x over previous
//
#include <hip/hip_runtime.h>
#include <hip/hip_bf16.h>

// Problem: features_1 [1,20000,256] f32, features_2 [1,8192,256] f32, map21 [8192] int
#define PP      8192
#define DIM     256
#define DIMP    272              // 256 + 16 pad dims (norm embedding in 4 of them)
#define NKF     17               // K fragments of 16
#define GS      (32 * DIMP)      // 8704 bf16 elems per 32-row group
#define NCHUNK  16               // column chunks (grid.y); chunk = 512 cols
#define TCOLS   16               // 32-col tiles per chunk
#define ROWBLK  256              // rows per main block (4 waves x 64)
#define NROWBLK (PP / ROWBLK)    // 32
#define TILEB   (32 * DIMP * 2)  // 17408 B per 32-col B tile
#define NBUF    4                // LDS ring buffers (depth-3 prefetch)

typedef __bf16 bf16_t;
using bf16x8 = __attribute__((ext_vector_type(8))) __bf16;
using bf16x4 = __attribute__((ext_vector_type(4))) __bf16;
using f32x4  = __attribute__((ext_vector_type(4))) float;
using f32x16 = __attribute__((ext_vector_type(16))) float;

typedef __attribute__((address_space(1))) void as1_void;
typedef __attribute__((address_space(3))) void as3_void;

#define C2    20.609929155556618          // 1/(T*ln2): -dist -> log2-domain logit
#define MEXP  (-340.0f)                   // fixed log2 shift (safe: see analysis)
#define COEF  ((float)(-(C2 * 1.4142135623730951) * 8388608.0))  // -C2*sqrt(2)*2^23
#define KBIAS ((float)((127.0 + 340.0) * 8388608.0))             // (127 - MEXP)*2^23
#define LN2   0.6931471805599453f

// ---------------------------------------------------------------------------
// Kernel 1: gather + bf16 convert into frag-major layout + norm-embedding pad
// dims + exact fp32 diagonal logit. Also zero-inits part_l / counters / out.
// One wave per row p; lane covers k = lane*4 .. +3.   (UNCHANGED)
// ---------------------------------------------------------------------------
__global__ __launch_bounds__(256) void nce_prep(
    const float* __restrict__ f1, const float* __restrict__ f2,
    const int* __restrict__ map,
    bf16_t* __restrict__ qb2, bf16_t* __restrict__ kb2,
    float* __restrict__ diag2, float* __restrict__ part_l,
    unsigned* __restrict__ cnt, float* __restrict__ out)
{
    const int tid  = threadIdx.x;
    const int wave = tid >> 6, lane = tid & 63;
    const int p    = blockIdx.x * 4 + wave;
    const int gtid = blockIdx.x * 256 + tid;

    if (gtid < PP) part_l[gtid] = 0.0f;
    if (gtid < NROWBLK) cnt[gtid] = 0u;
    if (gtid == 0) out[0] = 0.0f;

    const int idx = map[p];
    const f32x4 qv = *(const f32x4*)(f1 + (size_t)idx * DIM + lane * 4);
    const f32x4 kv = *(const f32x4*)(f2 + (size_t)p * DIM + lane * 4);

    float qs = qv[0]*qv[0] + qv[1]*qv[1] + qv[2]*qv[2] + qv[3]*qv[3];
    float ks = kv[0]*kv[0] + kv[1]*kv[1] + kv[2]*kv[2] + kv[3]*kv[3];
    const f32x4 dv = qv - kv;
    float ds = dv[0]*dv[0] + dv[1]*dv[1] + dv[2]*dv[2] + dv[3]*dv[3];

    bf16x4 qo, ko;
    #pragma unroll
    for (int i = 0; i < 4; ++i) { qo[i] = (bf16_t)qv[i]; ko[i] = (bf16_t)kv[i]; }

    const int G = p >> 5, l31 = p & 31;
    const int kk = lane >> 2, h = (lane >> 1) & 1, j0 = (lane & 1) * 4;
    const size_t base = (size_t)G * GS;
    const size_t off  = base + (size_t)(kk * 64 + h * 32 + l31) * 8 + j0;
    *(bf16x4*)(qb2 + off) = qo;
    *(bf16x4*)(kb2 + off) = ko;

    #pragma unroll
    for (int s = 32; s > 0; s >>= 1) {
        qs += __shfl_xor(qs, s);
        ks += __shfl_xor(ks, s);
        ds += __shfl_xor(ds, s);
    }

    // Pad frag kk=16 (dims 256..271). q' = [qhi,qlo,1,1,0..], k' = [1,1,khi,klo,0..]
    // so extra-dim dot = -(qs+ks)/2 with bf16 hi/lo split (norm error < 0.01).
    if (lane < 4) {
        const int hh = lane & 1;           // h of the pad block this lane writes
        bf16x8 v;
        #pragma unroll
        for (int i = 0; i < 8; ++i) v[i] = (bf16_t)0.0f;
        if (lane == 0) {                   // q', dims 256..263
            const float qh = -0.5f * qs;
            const bf16_t q1 = (bf16_t)qh;
            v[0] = q1; v[1] = (bf16_t)(qh - (float)q1);
            v[2] = (bf16_t)1.0f; v[3] = (bf16_t)1.0f;
        } else if (lane == 2) {            // k', dims 256..263
            const float kh = -0.5f * ks;
            const bf16_t k1 = (bf16_t)kh;
            v[0] = (bf16_t)1.0f; v[1] = (bf16_t)1.0f;
            v[2] = k1; v[3] = (bf16_t)(kh - (float)k1);
        }
        bf16_t* dstp = (lane < 2) ? qb2 : kb2;
        *(bf16x8*)(dstp + base + (size_t)(1024 + hh * 32 + l31) * 8) = v;
    }
    if (lane == 0)
        diag2[p] = (float)(-C2) * __builtin_amdgcn_sqrtf(ds);  // exact diag, log2
}

// ---------------------------------------------------------------------------
// Stage one 32-col B tile (17408 B, frag-major) into LDS via global_load_lds
// width-16. LDS dst = wave-uniform base (+ implicit lane*16).
// Waves 0-3 load 4x1KB each; wave 0 loads the 17th-fragment KB extra (5 loads).
// ---------------------------------------------------------------------------
__device__ __forceinline__ void stage(const bf16_t* __restrict__ kb2,
                                      int Gc, int wave, int lane, char* dst)
{
    __builtin_assume(wave >= 0 && wave < 4);
    __builtin_assume(lane >= 0 && lane < 64);
    const bf16_t* src = kb2 + (size_t)Gc * GS + wave * 512 + lane * 8;
    char* d = dst + wave * 1024;
    #pragma unroll
    for (int j = 0; j < 4; ++j)
        __builtin_amdgcn_global_load_lds((const as1_void*)(src + j * 2048),
                                         (as3_void*)(d + j * 4096), 16, 0, 0);
    if (wave == 0)   // last 1 KB (17th fragment block)
        __builtin_amdgcn_global_load_lds((const as1_void*)(src + 4 * 2048),
                                         (as3_void*)(d + 4 * 4096), 16, 0, 0);
}

// ---------------------------------------------------------------------------
// One pipeline phase (macro so l0/l1 stay direct constant-indexed locals —
// the round-2 function/pointer version spilled ~70 floats/thread to scratch:
// WRITE_SIZE 2MB -> 21MB).  Counted-vmcnt wait (+ lgkmcnt(0) race guard) +
// raw s_barrier: prefetch loads stay in flight ACROSS the barrier.  Then
// issue prefetch for tile T+3, ds_read + MFMA tile T under setprio(1),
// sqrt/exp2 epilogue.
// Ledger (4 loads/stage, wave0 5 — over-wait benign, vmcnt retires in order):
//   top of phase T outstanding = stages T,T+1,T+2 (12) -> vmcnt(8) retires
//   exactly stage T.  Tail: T=13 wait 8 (12 out), T=14 wait 4 (8 out),
//   T=15 wait 0 (4 out).  lgkmcnt(0) guarantees no wave crosses the barrier
//   with a ds_read of the about-to-be-overwritten buffer in flight.
// ---------------------------------------------------------------------------
#define PHASE(NW, DOPRE, T)                                                    \
  do {                                                                         \
    asm volatile("s_waitcnt vmcnt(%c0) lgkmcnt(0)\n\ts_barrier"                \
                 :: "i"(NW) : "memory");                                       \
    if (DOPRE) {                                                               \
        stage(kb2, c0g + (T) + 3, wave, lane, smem[((T) + 3) & 3]);            \
        __builtin_amdgcn_sched_barrier(0x7); /* keep VMEM/DS order */          \
    }                                                                          \
    const bf16_t* bp = (const bf16_t*)smem[(T) & 3] + lane * 8;                \
    f32x16 acc0 = {0,0,0,0,0,0,0,0,0,0,0,0,0,0,0,0};                          \
    f32x16 acc1 = {0,0,0,0,0,0,0,0,0,0,0,0,0,0,0,0};                          \
    __builtin_amdgcn_s_setprio(1);                                             \
    _Pragma("unroll")                                                          \
    for (int kk = 0; kk < NKF; ++kk) {                                         \
        const bf16x8 b = *(const bf16x8*)(bp + kk * 512);                      \
        acc0 = __builtin_amdgcn_mfma_f32_32x32x16_bf16(a0[kk], b, acc0,0,0,0); \
        acc1 = __builtin_amdgcn_mfma_f32_32x32x16_bf16(a1[kk], b, acc1,0,0,0); \
    }                                                                          \
    __builtin_amdgcn_s_setprio(0);                                             \
    /* acc = -dist^2/2.  2^(lg-MEXP) bitcast trick; negative -> clamp 0 */     \
    _Pragma("unroll")                                                          \
    for (int i = 0; i < 16; ++i) {                                             \
        const float t0 = __builtin_amdgcn_sqrtf(-acc0[i]);                     \
        const float u0 = fmaxf(fmaf(t0, COEF, KBIAS), 0.0f);                   \
        l0[i] += __uint_as_float((unsigned)u0);                                \
        const float t1 = __builtin_amdgcn_sqrtf(-acc1[i]);                     \
        const float u1 = fmaxf(fmaf(t1, COEF, KBIAS), 0.0f);                   \
        l1[i] += __uint_as_float((unsigned)u1);                                \
    }                                                                          \
  } while (0)

// ---------------------------------------------------------------------------
// Kernel 2: fused (QK' GEMM -> -dist^2/2) + fixed-shift exp2 accumulation +
// cross-block merge via atomicAdd + last-block final loss reduction.
// Wave = 64 rows (2 groups) x 32 cols; block = 4 waves = 256 rows.
// 4-buffer LDS ring, depth-3 prefetch, counted vmcnt (never 0 mid-loop),
// raw s_barrier (one per tile), setprio around MFMA cluster.  Steady-state
// loop is ROLLED (#pragma unroll 1) — full unroll spilled (round 2).
// ---------------------------------------------------------------------------
__global__ __launch_bounds__(256, 2) void nce_main(
    const bf16_t* __restrict__ qb2, const bf16_t* __restrict__ kb2,
    const float* __restrict__ diag2, float* __restrict__ part_l,
    unsigned* __restrict__ cnt, float* __restrict__ out)
{
    const int tid  = threadIdx.x, wave = tid >> 6, lane = tid & 63;
    const int l31  = lane & 31, h = lane >> 5;
    const int rb   = blockIdx.x;               // row-block 0..31 (256 rows)
    const int G0   = rb * 8 + wave * 2;        // this wave's first 32-row group
    const int c0g  = blockIdx.y * TCOLS;       // first col-group of chunk

    __shared__ __align__(16) char smem[NBUF][TILEB];
    __shared__ int s_last;

    // prologue: fill 3 of 4 ring slots (loads in flight behind the A-loads)
    stage(kb2, c0g + 0, wave, lane, smem[0]);
    stage(kb2, c0g + 1, wave, lane, smem[1]);
    stage(kb2, c0g + 2, wave, lane, smem[2]);

    // A fragments for 2 row groups: 2 x 17 x 4 = 136 VGPRs, 1KB/instr coalesced
    bf16x8 a0[NKF], a1[NKF];
    {
        const bf16_t* ap0 = qb2 + (size_t)G0 * GS + lane * 8;
        const bf16_t* ap1 = ap0 + GS;
        #pragma unroll
        for (int kk = 0; kk < NKF; ++kk) {
            a0[kk] = *(const bf16x8*)(ap0 + kk * 512);
            a1[kk] = *(const bf16x8*)(ap1 + kk * 512);
        }
    }

    float l0[16], l1[16];
    #pragma unroll
    for (int i = 0; i < 16; ++i) { l0[i] = 0.0f; l1[i] = 0.0f; }

    // steady state: tiles t..t+2 staged; prefetch t+3 each phase (t+3 <= 15)
    #pragma unroll 1
    for (int t = 0; t < 13; ++t)
        PHASE(8, true, t);
    // drain tail: t = 13,14,15 (no prefetch; waits 8 -> 4 -> 0)
    PHASE(8, false, 13);
    PHASE(4, false, 14);
    PHASE(0, false, 15);

    // sum l across the 32 column-lanes (plain adds — fixed shift, no max merge)
    #pragma unroll
    for (int s = 1; s < 32; s <<= 1) {
        #pragma unroll
        for (int i = 0; i < 16; ++i) {
            l0[i] += __shfl_xor(l0[i], s);
            l1[i] += __shfl_xor(l1[i], s);
        }
    }

    if (l31 == 0) {
        #pragma unroll
        for (int i = 0; i < 16; ++i) {
            const int r = (i & 3) + 8 * (i >> 2) + 4 * h;
            atomicAdd(&part_l[G0 * 32 + r], l0[i]);
            atomicAdd(&part_l[(G0 + 1) * 32 + r], l1[i]);
        }
    }

    __syncthreads();
    if (tid == 0) {
        __threadfence();
        s_last = (atomicAdd(&cnt[rb], 1u) == NCHUNK - 1) ? 1 : 0;
    }
    __syncthreads();
    if (s_last) {
        // all 16 chunk-blocks of this row-block done: finalize 256 rows
        const int row = rb * ROWBLK + tid;
        const float lf = atomicAdd(&part_l[row], 0.0f);   // coherent read
        float v = MEXP + __builtin_amdgcn_logf(lf) - diag2[row];  // log2 domain
        #pragma unroll
        for (int s = 1; s < 64; s <<= 1) v += __shfl_xor(v, s);
        __shared__ float red[4];
        if (lane == 0) red[wave] = v;
        __syncthreads();
        if (tid == 0)
            atomicAdd(out, (red[0] + red[1] + red[2] + red[3]) * (LN2 / (float)PP));
    }
}

// ---------------------------------------------------------------------------
extern "C" void kernel_launch(void* const* d_in, const int* in_sizes, int n_in,
                              void* d_out, int out_size, void* d_ws, size_t ws_size,
                              hipStream_t stream)
{
    const float* f1  = (const float*)d_in[0];   // [20000,256] f32
    const float* f2  = (const float*)d_in[1];   // [8192,256] f32
    const int*   map = (const int*)d_in[2];     // [8192] int
    float* out = (float*)d_out;

    // workspace layout (~8.98 MB)
    char* ws = (char*)d_ws;
    bf16_t*   qb2    = (bf16_t*)ws;                           // 256*8704*2 B
    bf16_t*   kb2    = qb2 + (size_t)256 * GS;                // 256*8704*2 B
    float*    diag2  = (float*)(ws + 2ull * 256 * GS * sizeof(bf16_t));
    float*    part_l = diag2 + PP;
    unsigned* cnt    = (unsigned*)(part_l + PP);

    nce_prep<<<PP / 4, 256, 0, stream>>>(f1, f2, map, qb2, kb2, diag2,
                                         part_l, cnt, out);
    nce_main<<<dim3(NROWBLK, NCHUNK), 256, 0, stream>>>(qb2, kb2, diag2,
                                                        part_l, cnt, out);
}